// Round 2
// baseline (1223.257 us; speedup 1.0000x reference)
//
#include <hip/hip_runtime.h>
#include <math.h>

// EulerAttention: B=2, S=4096, D=1024.
// Pipeline: [K1] fp32 QKV GEMM + cos/sin epilogue -> bf16 features (both batches)
//           per batch b:
//           [K2] bf16 MFMA NT GEMM: sim(fp32) = Qf @ Kf^T  (K=2048)
//           [K3] row softmax: fp32 sim -> bf16 P in place (row stride 8192)
//           [K4] bf16 MFMA NT GEMM: out = P @ Vt^T   (fp32 out)
// ws: Qf 33.5M | Kf 33.5M | Vt 16.8M | sim 67M (fp32, reused per batch) = ~151MB
//
// Precision note: sim ~ 640 +- ~15 (high-index features give cos(small)~1 ->
// big common-mode offset). bf16 storage of sim quantizes at step 2.0 -> +-3%
// weight noise -> 3.4e-3 output error (round 1 failure). sim MUST be fp32.

typedef __attribute__((ext_vector_type(8))) short bf16x8;
typedef __attribute__((ext_vector_type(4))) float f32x4;

__device__ __forceinline__ float b2f(unsigned short h) {
    union { unsigned int u; float f; } v; v.u = ((unsigned int)h) << 16; return v.f;
}
__device__ __forceinline__ unsigned short f2b(float f) {
    union { float f; unsigned int u; } v; v.f = f;
    unsigned int r = v.u + 0x7fffu + ((v.u >> 16) & 1u);
    return (unsigned short)(r >> 16);
}
__device__ __forceinline__ void storeC(unsigned short* p, float v) { *p = f2b(v); }
__device__ __forceinline__ void storeC(float* p, float v) { *p = v; }

// ---------------- K1: fp32 QKV projection + feature epilogue ----------------
// grid (16, 128, 3): x = n-block(64), y = m-block(64), z = {Q,K,V}
__global__ __launch_bounds__(256) void qkv_kernel(
    const float* __restrict__ x,
    const float* __restrict__ Wq, const float* __restrict__ bq,
    const float* __restrict__ Wk, const float* __restrict__ bk,
    const float* __restrict__ Wv, const float* __restrict__ bv,
    const float* __restrict__ phase,
    unsigned short* __restrict__ Qf, unsigned short* __restrict__ Kf,
    unsigned short* __restrict__ Vt)
{
    const int z = blockIdx.z;
    const float* W    = (z == 0) ? Wq : ((z == 1) ? Wk : Wv);
    const float* bias = (z == 0) ? bq : ((z == 1) ? bk : bv);
    const int m0 = blockIdx.y * 64;
    const int n0 = blockIdx.x * 64;

    __shared__ float As[16][68];   // [k][m], pad 4 -> float4 reads stay aligned
    __shared__ float Bs[16][68];   // [k][n]

    const int tid = threadIdx.x;
    const int tx = tid & 15, ty = tid >> 4;

    float acc[4][4];
#pragma unroll
    for (int i = 0; i < 4; i++)
#pragma unroll
        for (int j = 0; j < 4; j++) acc[i][j] = 0.f;

    for (int k0 = 0; k0 < 1024; k0 += 16) {
#pragma unroll
        for (int i = 0; i < 4; i++) {
            int idx = tid + 256 * i;          // 0..1023
            int row = idx >> 4;               // 0..63
            int col = idx & 15;               // 0..15
            As[col][row] = x[(size_t)(m0 + row) * 1024 + k0 + col];
            Bs[col][row] = W[(size_t)(n0 + row) * 1024 + k0 + col];
        }
        __syncthreads();
#pragma unroll
        for (int kk = 0; kk < 16; kk++) {
            float4 av = *(const float4*)&As[kk][ty * 4];
            float4 bv4 = *(const float4*)&Bs[kk][tx * 4];
            float a4[4] = { av.x, av.y, av.z, av.w };
            float b4[4] = { bv4.x, bv4.y, bv4.z, bv4.w };
#pragma unroll
            for (int i = 0; i < 4; i++)
#pragma unroll
                for (int j = 0; j < 4; j++)
                    acc[i][j] = fmaf(a4[i], b4[j], acc[i][j]);
        }
        __syncthreads();
    }

    const float w0 = (float)(2.0 * M_PI / 1024.0);
#pragma unroll
    for (int i = 0; i < 4; i++) {
        int rg = m0 + ty * 4 + i;             // global row in [0, 8192)
        int bb = rg >> 12;                    // batch
        int s  = rg & 4095;                   // seq pos
#pragma unroll
        for (int j = 0; j < 4; j++) {
            int n = n0 + tx * 4 + j;
            float val = acc[i][j] + bias[n];
            if (z == 2) {
                // V stored transposed: Vt[b][d][t]
                Vt[((size_t)bb * 1024 + n) * 4096 + s] = f2b(val);
            } else {
                float wl  = (float)(n + 1) * w0;
                float inv = 1.0f / (wl + 1e-8f);
                float th  = fmaf(val, inv, phase[n]);
                float sn, cs;
                sincosf(th, &sn, &cs);
                unsigned short* dst = (z == 0) ? Qf : Kf;
                size_t base = ((size_t)bb * 4096 + s) * 2048;
                dst[base + n]        = f2b(cs);
                dst[base + 1024 + n] = f2b(sn);
            }
        }
    }
}

// ---------------- K2/K4: bf16 MFMA NT GEMM ----------------
// C[m][n] = sum_k A[m][k] * Bm[n][k]; 128x128 tile, BK=32, 4 waves (2x2),
// each wave 64x64 via 4x4 mfma_f32_16x16x32_bf16. lda/ldb in elements.
template <typename OutT>
__global__ __launch_bounds__(256) void gemm_nt(
    const unsigned short* __restrict__ A,
    const unsigned short* __restrict__ Bm,
    OutT* __restrict__ C,
    int M, int N, int K, int lda, int ldb)
{
    const int m0 = blockIdx.y * 128;
    const int n0 = blockIdx.x * 128;

    __shared__ unsigned short As[128 * 40];  // stride 40 shorts (pad 8), rows 16B-aligned
    __shared__ unsigned short Bs[128 * 40];

    const int tid  = threadIdx.x;
    const int lane = tid & 63;
    const int w    = tid >> 6;
    const int wr   = w >> 1, wc = w & 1;
    const int l15  = lane & 15, q = lane >> 4;

    f32x4 acc[4][4];
#pragma unroll
    for (int a = 0; a < 4; a++)
#pragma unroll
        for (int b = 0; b < 4; b++) acc[a][b] = (f32x4){0.f, 0.f, 0.f, 0.f};

    for (int k0 = 0; k0 < K; k0 += 32) {
#pragma unroll
        for (int i = 0; i < 2; i++) {
            int idx = tid + 256 * i;          // 0..511 chunks of 8 bf16
            int row = idx >> 2;               // 0..127
            int cc  = idx & 3;                // 0..3 (8 shorts each)
            *(uint4*)&As[row * 40 + cc * 8] =
                *(const uint4*)&A[(size_t)(m0 + row) * lda + k0 + cc * 8];
            *(uint4*)&Bs[row * 40 + cc * 8] =
                *(const uint4*)&Bm[(size_t)(n0 + row) * ldb + k0 + cc * 8];
        }
        __syncthreads();
        bf16x8 af[4], bfr[4];
#pragma unroll
        for (int mt = 0; mt < 4; mt++)
            af[mt] = *(const bf16x8*)&As[(wr * 64 + mt * 16 + l15) * 40 + q * 8];
#pragma unroll
        for (int nt = 0; nt < 4; nt++)
            bfr[nt] = *(const bf16x8*)&Bs[(wc * 64 + nt * 16 + l15) * 40 + q * 8];
#pragma unroll
        for (int mt = 0; mt < 4; mt++)
#pragma unroll
            for (int nt = 0; nt < 4; nt++)
                acc[mt][nt] = __builtin_amdgcn_mfma_f32_16x16x32_bf16(
                    af[mt], bfr[nt], acc[mt][nt], 0, 0, 0);
        __syncthreads();
    }

#pragma unroll
    for (int mt = 0; mt < 4; mt++) {
#pragma unroll
        for (int nt = 0; nt < 4; nt++) {
            int n = n0 + wc * 64 + nt * 16 + l15;
#pragma unroll
            for (int r = 0; r < 4; r++) {
                int m = m0 + wr * 64 + mt * 16 + q * 4 + r;  // C/D: col=lane&15, row=quad*4+reg
                storeC(&C[(size_t)m * N + n], acc[mt][nt][r]);
            }
        }
    }
}

// ---------------- K3: row softmax, fp32 sim -> bf16 P in place ----------------
// One block per row. Reads 4096 fp32 at sim + row*4096; writes 4096 bf16 at
// (ushort*)sim + row*8192 (same byte range start; all reads precede writes).
__global__ __launch_bounds__(256) void softmax_kernel(float* __restrict__ sim)
{
    const size_t row = blockIdx.x;
    const float* pin = sim + row * 4096;
    unsigned short* pout = (unsigned short*)sim + row * 8192;
    const int tid = threadIdx.x;

    float v[16];
#pragma unroll
    for (int i = 0; i < 4; i++) {
        float4 d = ((const float4*)pin)[tid * 4 + i];
        v[4 * i + 0] = d.x * 0.03125f;
        v[4 * i + 1] = d.y * 0.03125f;
        v[4 * i + 2] = d.z * 0.03125f;
        v[4 * i + 3] = d.w * 0.03125f;
    }

    float m = v[0];
#pragma unroll
    for (int i = 1; i < 16; i++) m = fmaxf(m, v[i]);
    for (int o = 32; o > 0; o >>= 1) m = fmaxf(m, __shfl_xor(m, o));
    __shared__ float red[4];
    if ((tid & 63) == 0) red[tid >> 6] = m;
    __syncthreads();
    m = fmaxf(fmaxf(red[0], red[1]), fmaxf(red[2], red[3]));
    __syncthreads();   // protect red[] before reuse

    float e[16];
    float s = 0.f;
#pragma unroll
    for (int i = 0; i < 16; i++) { e[i] = expf(v[i] - m); s += e[i]; }
    for (int o = 32; o > 0; o >>= 1) s += __shfl_xor(s, o);
    if ((tid & 63) == 0) red[tid >> 6] = s;
    __syncthreads();
    float l = (red[0] + red[1]) + (red[2] + red[3]);
    float inv = 1.0f / l;

#pragma unroll
    for (int c = 0; c < 2; c++) {
        unsigned int wds[4];
#pragma unroll
        for (int i = 0; i < 4; i++) {
            unsigned int lo = f2b(e[c * 8 + 2 * i] * inv);
            unsigned int hi = f2b(e[c * 8 + 2 * i + 1] * inv);
            wds[i] = lo | (hi << 16);
        }
        uint4 o4; o4.x = wds[0]; o4.y = wds[1]; o4.z = wds[2]; o4.w = wds[3];
        ((uint4*)pout)[tid * 2 + c] = o4;
    }
}

extern "C" void kernel_launch(void* const* d_in, const int* in_sizes, int n_in,
                              void* d_out, int out_size, void* d_ws, size_t ws_size,
                              hipStream_t stream)
{
    const float* x  = (const float*)d_in[0];
    const float* Wq = (const float*)d_in[1];
    const float* bq = (const float*)d_in[2];
    const float* Wk = (const float*)d_in[3];
    const float* bk = (const float*)d_in[4];
    const float* Wv = (const float*)d_in[5];
    const float* bv = (const float*)d_in[6];
    const float* ph = (const float*)d_in[7];

    unsigned short* Qf = (unsigned short*)d_ws;             // [2][4096][2048] bf16
    unsigned short* Kf = Qf + (size_t)2 * 4096 * 2048;      // [2][4096][2048] bf16
    unsigned short* Vt = Kf + (size_t)2 * 4096 * 2048;      // [2][1024][4096] bf16
    float*         sim = (float*)(Vt + (size_t)2 * 1024 * 4096);  // [4096][4096] fp32, per batch

    qkv_kernel<<<dim3(16, 128, 3), 256, 0, stream>>>(x, Wq, bq, Wk, bk, Wv, bv, ph,
                                                     Qf, Kf, Vt);

    for (int b = 0; b < 2; b++) {
        const unsigned short* Qb = Qf + (size_t)b * 4096 * 2048;
        const unsigned short* Kb = Kf + (size_t)b * 4096 * 2048;
        const unsigned short* Vb = Vt + (size_t)b * 1024 * 4096;
        float* outb = (float*)d_out + (size_t)b * 4096 * 1024;

        // sim = Qf @ Kf^T, fp32 out
        gemm_nt<float><<<dim3(32, 32), 256, 0, stream>>>(Qb, Kb, sim,
                                                         4096, 4096, 2048, 2048, 2048);
        // softmax rows, bf16 P in place (row stride 8192 shorts)
        softmax_kernel<<<4096, 256, 0, stream>>>(sim);
        // out = P @ Vt^T
        gemm_nt<float><<<dim3(8, 32), 256, 0, stream>>>((const unsigned short*)sim, Vb, outb,
                                                        4096, 1024, 4096, 8192, 4096);
    }
}

// Round 3
// 1172.609 us; speedup vs baseline: 1.0432x; 1.0432x over previous
//
#include <hip/hip_runtime.h>
#include <math.h>

// EulerAttention: B=2, S=4096, D=1024.
// Pipeline: [K0] split fp32 -> (hi,lo) bf16 for x and stacked W  (elementwise)
//           [K1] split-bf16 MFMA GEMM (3-term: hh + hl + lh), M=8192 N=3072 K=1024,
//                epilogue: bias + sincos -> Qf/Kf bf16 features, V -> Vt bf16
//           per batch b:
//           [K2] bf16 MFMA NT GEMM: sim(fp32) = Qf @ Kf^T  (K=2048)
//           [K3] row softmax: fp32 sim -> bf16 P in place (row stride 8192)
//           [K4] bf16 MFMA NT GEMM: out = P @ Vt^T   (fp32 out)
// ws: [sim 67MB fp32 (aliases Xhi|Xlo|Whi|Wlo 46MB used only before K2)]
//     [Qf 33.5MB][Kf 33.5MB][Vt 16.8MB]  = ~151MB
//
// Precision notes (load-bearing):
//  - sim ~ 640 +- ~15 (cos(small)~1 common mode). sim MUST be fp32 (R1 failure).
//  - Q/K need near-fp32 precision: inv_wl[0]~163 amplifies Q error into theta.
//    3-term split-bf16 leaves ~4e-6 Q error -> 7e-4 rad worst; bf16 feature
//    storage (+-4e-3) dominates. 2-term split is NOT enough (0.3 rad @ n=0).

typedef __attribute__((ext_vector_type(8))) short bf16x8;
typedef __attribute__((ext_vector_type(4))) float f32x4;

__device__ __forceinline__ float b2f(unsigned short h) {
    union { unsigned int u; float f; } v; v.u = ((unsigned int)h) << 16; return v.f;
}
__device__ __forceinline__ unsigned short f2b(float f) {
    union { float f; unsigned int u; } v; v.f = f;
    unsigned int r = v.u + 0x7fffu + ((v.u >> 16) & 1u);
    return (unsigned short)(r >> 16);
}
__device__ __forceinline__ void storeC(unsigned short* p, float v) { *p = f2b(v); }
__device__ __forceinline__ void storeC(float* p, float v) { *p = v; }

// ---------------- K0: fp32 -> (hi, lo) bf16 split ----------------
__global__ __launch_bounds__(256) void split_kernel(
    const float* __restrict__ src,
    unsigned short* __restrict__ hi, unsigned short* __restrict__ lo, int n4)
{
    int i = blockIdx.x * 256 + threadIdx.x;
    if (i >= n4) return;
    float4 v = ((const float4*)src)[i];
    float f[4] = { v.x, v.y, v.z, v.w };
    unsigned short h[4], l[4];
#pragma unroll
    for (int j = 0; j < 4; j++) {
        h[j] = f2b(f[j]);
        float r = f[j] - b2f(h[j]);
        l[j] = f2b(r);
    }
    uint2 ho, lv;
    ho.x = (unsigned int)h[0] | ((unsigned int)h[1] << 16);
    ho.y = (unsigned int)h[2] | ((unsigned int)h[3] << 16);
    lv.x = (unsigned int)l[0] | ((unsigned int)l[1] << 16);
    lv.y = (unsigned int)l[2] | ((unsigned int)l[3] << 16);
    ((uint2*)hi)[i] = ho;
    ((uint2*)lo)[i] = lv;
}

// ---------------- K1: split-bf16 MFMA projection GEMM ----------------
// C = Xhi@W^T via 3-term split; grid (24, 64): n0 = bx*128 in [0,3072), m0 = by*128.
// Blocks 0-7 of n -> Q, 8-15 -> K, 16-23 -> V (z = n0>>10, uniform per block).
__global__ __launch_bounds__(256) void proj_kernel(
    const unsigned short* __restrict__ Xhi, const unsigned short* __restrict__ Xlo,
    const unsigned short* __restrict__ Whi, const unsigned short* __restrict__ Wlo,
    const float* __restrict__ bq, const float* __restrict__ bk,
    const float* __restrict__ bv, const float* __restrict__ phase,
    unsigned short* __restrict__ Qf, unsigned short* __restrict__ Kf,
    unsigned short* __restrict__ Vt)
{
    const int m0 = blockIdx.y * 128;
    const int n0 = blockIdx.x * 128;

    __shared__ unsigned short Ah[128 * 40], Al[128 * 40];
    __shared__ unsigned short Bh[128 * 40], Bl[128 * 40];

    const int tid  = threadIdx.x;
    const int lane = tid & 63;
    const int w    = tid >> 6;
    const int wr   = w >> 1, wc = w & 1;
    const int l15  = lane & 15, q = lane >> 4;

    f32x4 acc[4][4];
#pragma unroll
    for (int a = 0; a < 4; a++)
#pragma unroll
        for (int b = 0; b < 4; b++) acc[a][b] = (f32x4){0.f, 0.f, 0.f, 0.f};

    for (int k0 = 0; k0 < 1024; k0 += 32) {
#pragma unroll
        for (int i = 0; i < 2; i++) {
            int idx = tid + 256 * i;
            int row = idx >> 2;
            int cc  = idx & 3;
            size_t ga = (size_t)(m0 + row) * 1024 + k0 + cc * 8;
            size_t gb = (size_t)(n0 + row) * 1024 + k0 + cc * 8;
            *(uint4*)&Ah[row * 40 + cc * 8] = *(const uint4*)&Xhi[ga];
            *(uint4*)&Al[row * 40 + cc * 8] = *(const uint4*)&Xlo[ga];
            *(uint4*)&Bh[row * 40 + cc * 8] = *(const uint4*)&Whi[gb];
            *(uint4*)&Bl[row * 40 + cc * 8] = *(const uint4*)&Wlo[gb];
        }
        __syncthreads();
        bf16x8 ah[4], al[4], bh[4], bl[4];
#pragma unroll
        for (int mt = 0; mt < 4; mt++) {
            int off = (wr * 64 + mt * 16 + l15) * 40 + q * 8;
            ah[mt] = *(const bf16x8*)&Ah[off];
            al[mt] = *(const bf16x8*)&Al[off];
        }
#pragma unroll
        for (int nt = 0; nt < 4; nt++) {
            int off = (wc * 64 + nt * 16 + l15) * 40 + q * 8;
            bh[nt] = *(const bf16x8*)&Bh[off];
            bl[nt] = *(const bf16x8*)&Bl[off];
        }
#pragma unroll
        for (int mt = 0; mt < 4; mt++)
#pragma unroll
            for (int nt = 0; nt < 4; nt++) {
                acc[mt][nt] = __builtin_amdgcn_mfma_f32_16x16x32_bf16(
                    ah[mt], bh[nt], acc[mt][nt], 0, 0, 0);
                acc[mt][nt] = __builtin_amdgcn_mfma_f32_16x16x32_bf16(
                    ah[mt], bl[nt], acc[mt][nt], 0, 0, 0);
                acc[mt][nt] = __builtin_amdgcn_mfma_f32_16x16x32_bf16(
                    al[mt], bh[nt], acc[mt][nt], 0, 0, 0);
            }
        __syncthreads();
    }

    const int z = n0 >> 10;                   // 0=Q, 1=K, 2=V
    const float* bias = (z == 0) ? bq : ((z == 1) ? bk : bv);
    const float w0 = (float)(2.0 * M_PI / 1024.0);

#pragma unroll
    for (int mt = 0; mt < 4; mt++) {
#pragma unroll
        for (int nt = 0; nt < 4; nt++) {
            int n = n0 + wc * 64 + nt * 16 + l15;
            int f = n & 1023;
#pragma unroll
            for (int r = 0; r < 4; r++) {
                int m  = m0 + wr * 64 + mt * 16 + q * 4 + r;   // row in [0,8192)
                int bb = m >> 12;
                int s  = m & 4095;
                float val = acc[mt][nt][r] + bias[f];
                if (z == 2) {
                    Vt[((size_t)bb * 1024 + f) * 4096 + s] = f2b(val);
                } else {
                    float wl  = (float)(f + 1) * w0;
                    float inv = 1.0f / (wl + 1e-8f);
                    float th  = fmaf(val, inv, phase[f]);
                    float sn, cs;
                    sincosf(th, &sn, &cs);
                    unsigned short* dst = (z == 0) ? Qf : Kf;
                    size_t base = ((size_t)bb * 4096 + s) * 2048;
                    dst[base + f]        = f2b(cs);
                    dst[base + 1024 + f] = f2b(sn);
                }
            }
        }
    }
}

// ---------------- K2/K4: bf16 MFMA NT GEMM ----------------
// C[m][n] = sum_k A[m][k] * Bm[n][k]; 128x128 tile, BK=32, 4 waves (2x2),
// each wave 64x64 via 4x4 mfma_f32_16x16x32_bf16. lda/ldb in elements.
template <typename OutT>
__global__ __launch_bounds__(256) void gemm_nt(
    const unsigned short* __restrict__ A,
    const unsigned short* __restrict__ Bm,
    OutT* __restrict__ C,
    int M, int N, int K, int lda, int ldb)
{
    const int m0 = blockIdx.y * 128;
    const int n0 = blockIdx.x * 128;

    __shared__ unsigned short As[128 * 40];  // stride 40 shorts (pad 8), rows 16B-aligned
    __shared__ unsigned short Bs[128 * 40];

    const int tid  = threadIdx.x;
    const int lane = tid & 63;
    const int w    = tid >> 6;
    const int wr   = w >> 1, wc = w & 1;
    const int l15  = lane & 15, q = lane >> 4;

    f32x4 acc[4][4];
#pragma unroll
    for (int a = 0; a < 4; a++)
#pragma unroll
        for (int b = 0; b < 4; b++) acc[a][b] = (f32x4){0.f, 0.f, 0.f, 0.f};

    for (int k0 = 0; k0 < K; k0 += 32) {
#pragma unroll
        for (int i = 0; i < 2; i++) {
            int idx = tid + 256 * i;          // 0..511 chunks of 8 bf16
            int row = idx >> 2;               // 0..127
            int cc  = idx & 3;                // 0..3 (8 shorts each)
            *(uint4*)&As[row * 40 + cc * 8] =
                *(const uint4*)&A[(size_t)(m0 + row) * lda + k0 + cc * 8];
            *(uint4*)&Bs[row * 40 + cc * 8] =
                *(const uint4*)&Bm[(size_t)(n0 + row) * ldb + k0 + cc * 8];
        }
        __syncthreads();
        bf16x8 af[4], bfr[4];
#pragma unroll
        for (int mt = 0; mt < 4; mt++)
            af[mt] = *(const bf16x8*)&As[(wr * 64 + mt * 16 + l15) * 40 + q * 8];
#pragma unroll
        for (int nt = 0; nt < 4; nt++)
            bfr[nt] = *(const bf16x8*)&Bs[(wc * 64 + nt * 16 + l15) * 40 + q * 8];
#pragma unroll
        for (int mt = 0; mt < 4; mt++)
#pragma unroll
            for (int nt = 0; nt < 4; nt++)
                acc[mt][nt] = __builtin_amdgcn_mfma_f32_16x16x32_bf16(
                    af[mt], bfr[nt], acc[mt][nt], 0, 0, 0);
        __syncthreads();
    }

#pragma unroll
    for (int mt = 0; mt < 4; mt++) {
#pragma unroll
        for (int nt = 0; nt < 4; nt++) {
            int n = n0 + wc * 64 + nt * 16 + l15;
#pragma unroll
            for (int r = 0; r < 4; r++) {
                int m = m0 + wr * 64 + mt * 16 + q * 4 + r;  // C/D: col=lane&15, row=quad*4+reg
                storeC(&C[(size_t)m * N + n], acc[mt][nt][r]);
            }
        }
    }
}

// ---------------- K3: row softmax, fp32 sim -> bf16 P in place ----------------
// One block per row. Reads 4096 fp32 at sim + row*4096; writes 4096 bf16 at
// (ushort*)sim + row*8192 (same byte range start; all reads precede writes).
__global__ __launch_bounds__(256) void softmax_kernel(float* __restrict__ sim)
{
    const size_t row = blockIdx.x;
    const float* pin = sim + row * 4096;
    unsigned short* pout = (unsigned short*)sim + row * 8192;
    const int tid = threadIdx.x;

    float v[16];
#pragma unroll
    for (int i = 0; i < 4; i++) {
        float4 d = ((const float4*)pin)[tid * 4 + i];
        v[4 * i + 0] = d.x * 0.03125f;
        v[4 * i + 1] = d.y * 0.03125f;
        v[4 * i + 2] = d.z * 0.03125f;
        v[4 * i + 3] = d.w * 0.03125f;
    }

    float m = v[0];
#pragma unroll
    for (int i = 1; i < 16; i++) m = fmaxf(m, v[i]);
    for (int o = 32; o > 0; o >>= 1) m = fmaxf(m, __shfl_xor(m, o));
    __shared__ float red[4];
    if ((tid & 63) == 0) red[tid >> 6] = m;
    __syncthreads();
    m = fmaxf(fmaxf(red[0], red[1]), fmaxf(red[2], red[3]));
    __syncthreads();   // protect red[] before reuse

    float e[16];
    float s = 0.f;
#pragma unroll
    for (int i = 0; i < 16; i++) { e[i] = expf(v[i] - m); s += e[i]; }
    for (int o = 32; o > 0; o >>= 1) s += __shfl_xor(s, o);
    if ((tid & 63) == 0) red[tid >> 6] = s;
    __syncthreads();
    float l = (red[0] + red[1]) + (red[2] + red[3]);
    float inv = 1.0f / l;

#pragma unroll
    for (int c = 0; c < 2; c++) {
        unsigned int wds[4];
#pragma unroll
        for (int i = 0; i < 4; i++) {
            unsigned int lo = f2b(e[c * 8 + 2 * i] * inv);
            unsigned int hi = f2b(e[c * 8 + 2 * i + 1] * inv);
            wds[i] = lo | (hi << 16);
        }
        uint4 o4; o4.x = wds[0]; o4.y = wds[1]; o4.z = wds[2]; o4.w = wds[3];
        ((uint4*)pout)[tid * 2 + c] = o4;
    }
}

extern "C" void kernel_launch(void* const* d_in, const int* in_sizes, int n_in,
                              void* d_out, int out_size, void* d_ws, size_t ws_size,
                              hipStream_t stream)
{
    const float* x  = (const float*)d_in[0];
    const float* Wq = (const float*)d_in[1];
    const float* bq = (const float*)d_in[2];
    const float* Wk = (const float*)d_in[3];
    const float* bk = (const float*)d_in[4];
    const float* Wv = (const float*)d_in[5];
    const float* bv = (const float*)d_in[6];
    const float* ph = (const float*)d_in[7];

    char* ws = (char*)d_ws;
    // Region A (first 67.1MB): Xhi|Xlo|Whi|Wlo (46.1MB) before K2; sim fp32 after.
    unsigned short* Xhi = (unsigned short*)ws;                    // 8192*1024
    unsigned short* Xlo = Xhi + (size_t)8192 * 1024;
    unsigned short* Whi = Xlo + (size_t)8192 * 1024;              // 3072*1024 stacked
    unsigned short* Wlo = Whi + (size_t)3072 * 1024;
    float*          sim = (float*)ws;                             // 4096*4096 fp32
    // Region B:
    unsigned short* Qf = (unsigned short*)(ws + (size_t)4096 * 4096 * 4);  // [2][4096][2048]
    unsigned short* Kf = Qf + (size_t)2 * 4096 * 2048;                     // [2][4096][2048]
    unsigned short* Vt = Kf + (size_t)2 * 4096 * 2048;                     // [2][1024][4096]

    // K0: splits
    split_kernel<<<8192, 256, 0, stream>>>(x,  Xhi, Xlo, 8192 * 1024 / 4);
    split_kernel<<<1024, 256, 0, stream>>>(Wq, Whi,                        Wlo,                        1024 * 1024 / 4);
    split_kernel<<<1024, 256, 0, stream>>>(Wk, Whi + (size_t)1024 * 1024,  Wlo + (size_t)1024 * 1024,  1024 * 1024 / 4);
    split_kernel<<<1024, 256, 0, stream>>>(Wv, Whi + (size_t)2048 * 1024,  Wlo + (size_t)2048 * 1024,  1024 * 1024 / 4);

    // K1: split-bf16 MFMA projection + feature epilogue
    proj_kernel<<<dim3(24, 64), 256, 0, stream>>>(Xhi, Xlo, Whi, Wlo,
                                                  bq, bk, bv, ph, Qf, Kf, Vt);

    for (int b = 0; b < 2; b++) {
        const unsigned short* Qb = Qf + (size_t)b * 4096 * 2048;
        const unsigned short* Kb = Kf + (size_t)b * 4096 * 2048;
        const unsigned short* Vb = Vt + (size_t)b * 1024 * 4096;
        float* outb = (float*)d_out + (size_t)b * 4096 * 1024;

        // sim = Qf @ Kf^T, fp32 out
        gemm_nt<float><<<dim3(32, 32), 256, 0, stream>>>(Qb, Kb, sim,
                                                         4096, 4096, 2048, 2048, 2048);
        // softmax rows, bf16 P in place (row stride 8192 shorts)
        softmax_kernel<<<4096, 256, 0, stream>>>(sim);
        // out = P @ Vt^T
        gemm_nt<float><<<dim3(8, 32), 256, 0, stream>>>((const unsigned short*)sim, Vb, outb,
                                                        4096, 1024, 4096, 8192, 4096);
    }
}

// Round 4
// 735.130 us; speedup vs baseline: 1.6640x; 1.5951x over previous
//
#include <hip/hip_runtime.h>
#include <math.h>

// EulerAttention: B=2, S=4096, D=1024.
// Pipeline: [K0] split fp32 -> (hi,lo) bf16 for x and stacked W  (elementwise)
//           [K1] split-bf16 MFMA GEMM (3-term: hh + hl + lh), M=8192 N=3072 K=1024,
//                epilogue: bias + HW-trig sincos -> Qf/Kf bf16 features, V -> Vt bf16
//           per batch b:
//           [K2] bf16 MFMA NT GEMM: sim(fp32) = Qf @ Kf^T  (K=2048)
//           [K3] row softmax: fp32 sim -> bf16 P in place (row stride 8192)
//           [K4] bf16 MFMA NT GEMM: out = P @ Vt^T   (fp32 out)
// ws: [sim 67MB fp32 (aliases Xhi|Xlo|Whi|Wlo 46MB used only before K2)]
//     [Qf 33.5MB][Kf 33.5MB][Vt 16.8MB]  = ~151MB
//
// Precision notes (load-bearing):
//  - sim ~ 640 +- ~15 (cos(small)~1 common mode). sim MUST be fp32 (R1 failure).
//  - Q/K need near-fp32 precision: inv_wl[0]~163 amplifies Q error into theta.
//    3-term split-bf16 leaves ~4e-6 Q error; bf16 feature storage dominates.
//  - R3 failure mode: libm sincosf call + high reg pressure -> scratch spill
//    -> 3.2GB phantom HBM writes. Epilogue trig MUST be branch-free inline
//    (v_sin_f32/v_cos_f32, revolutions input, fract-reduced).

typedef __attribute__((ext_vector_type(8))) short bf16x8;
typedef __attribute__((ext_vector_type(4))) float f32x4;

__device__ __forceinline__ float b2f(unsigned short h) {
    union { unsigned int u; float f; } v; v.u = ((unsigned int)h) << 16; return v.f;
}
__device__ __forceinline__ unsigned short f2b(float f) {
    union { float f; unsigned int u; } v; v.f = f;
    unsigned int r = v.u + 0x7fffu + ((v.u >> 16) & 1u);
    return (unsigned short)(r >> 16);
}
__device__ __forceinline__ void storeC(unsigned short* p, float v) { *p = f2b(v); }
__device__ __forceinline__ void storeC(float* p, float v) { *p = v; }

// Branch-free sin/cos of th (radians), |th| < ~1e5. HW v_sin/v_cos take
// REVOLUTIONS: D = sin(S0 * 2pi); reduce to [0,1) via floor.
__device__ __forceinline__ void fast_sincos(float th, float* sn, float* cs) {
    float rev = th * 0.15915494309189535f;   // th / (2*pi)
    float fr  = rev - floorf(rev);           // [0,1)
    float s, c;
    asm("v_sin_f32 %0, %1" : "=v"(s) : "v"(fr));
    asm("v_cos_f32 %0, %1" : "=v"(c) : "v"(fr));
    *sn = s; *cs = c;
}

// ---------------- K0: fp32 -> (hi, lo) bf16 split ----------------
__global__ __launch_bounds__(256) void split_kernel(
    const float* __restrict__ src,
    unsigned short* __restrict__ hi, unsigned short* __restrict__ lo, int n4)
{
    int i = blockIdx.x * 256 + threadIdx.x;
    if (i >= n4) return;
    float4 v = ((const float4*)src)[i];
    float f[4] = { v.x, v.y, v.z, v.w };
    unsigned short h[4], l[4];
#pragma unroll
    for (int j = 0; j < 4; j++) {
        h[j] = f2b(f[j]);
        float r = f[j] - b2f(h[j]);
        l[j] = f2b(r);
    }
    uint2 ho, lv;
    ho.x = (unsigned int)h[0] | ((unsigned int)h[1] << 16);
    ho.y = (unsigned int)h[2] | ((unsigned int)h[3] << 16);
    lv.x = (unsigned int)l[0] | ((unsigned int)l[1] << 16);
    lv.y = (unsigned int)l[2] | ((unsigned int)l[3] << 16);
    ((uint2*)hi)[i] = ho;
    ((uint2*)lo)[i] = lv;
}

// ---------------- K1: split-bf16 MFMA projection GEMM ----------------
// C = X@W^T via 3-term split; grid (24, 64): n0 = bx*128 in [0,3072), m0 = by*128.
// n-blocks 0-7 -> Q, 8-15 -> K, 16-23 -> V (z = n0>>10, uniform per block).
__global__ __launch_bounds__(256, 2) void proj_kernel(
    const unsigned short* __restrict__ Xhi, const unsigned short* __restrict__ Xlo,
    const unsigned short* __restrict__ Whi, const unsigned short* __restrict__ Wlo,
    const float* __restrict__ bq, const float* __restrict__ bk,
    const float* __restrict__ bv, const float* __restrict__ phase,
    unsigned short* __restrict__ Qf, unsigned short* __restrict__ Kf,
    unsigned short* __restrict__ Vt)
{
    const int m0 = blockIdx.y * 128;
    const int n0 = blockIdx.x * 128;

    __shared__ unsigned short Ah[128 * 40], Al[128 * 40];
    __shared__ unsigned short Bh[128 * 40], Bl[128 * 40];

    const int tid  = threadIdx.x;
    const int lane = tid & 63;
    const int w    = tid >> 6;
    const int wr   = w >> 1, wc = w & 1;
    const int l15  = lane & 15, q = lane >> 4;

    f32x4 acc[4][4];
#pragma unroll
    for (int a = 0; a < 4; a++)
#pragma unroll
        for (int b = 0; b < 4; b++) acc[a][b] = (f32x4){0.f, 0.f, 0.f, 0.f};

    for (int k0 = 0; k0 < 1024; k0 += 32) {
#pragma unroll
        for (int i = 0; i < 2; i++) {
            int idx = tid + 256 * i;
            int row = idx >> 2;
            int cc  = idx & 3;
            size_t ga = (size_t)(m0 + row) * 1024 + k0 + cc * 8;
            size_t gb = (size_t)(n0 + row) * 1024 + k0 + cc * 8;
            *(uint4*)&Ah[row * 40 + cc * 8] = *(const uint4*)&Xhi[ga];
            *(uint4*)&Al[row * 40 + cc * 8] = *(const uint4*)&Xlo[ga];
            *(uint4*)&Bh[row * 40 + cc * 8] = *(const uint4*)&Whi[gb];
            *(uint4*)&Bl[row * 40 + cc * 8] = *(const uint4*)&Wlo[gb];
        }
        __syncthreads();
        bf16x8 ah[4], al[4];
#pragma unroll
        for (int mt = 0; mt < 4; mt++) {
            int off = (wr * 64 + mt * 16 + l15) * 40 + q * 8;
            ah[mt] = *(const bf16x8*)&Ah[off];
            al[mt] = *(const bf16x8*)&Al[off];
        }
#pragma unroll
        for (int nt = 0; nt < 4; nt++) {
            int off = (wc * 64 + nt * 16 + l15) * 40 + q * 8;
            bf16x8 bh = *(const bf16x8*)&Bh[off];
            bf16x8 bl = *(const bf16x8*)&Bl[off];
#pragma unroll
            for (int mt = 0; mt < 4; mt++) {
                acc[mt][nt] = __builtin_amdgcn_mfma_f32_16x16x32_bf16(
                    ah[mt], bh, acc[mt][nt], 0, 0, 0);
                acc[mt][nt] = __builtin_amdgcn_mfma_f32_16x16x32_bf16(
                    ah[mt], bl, acc[mt][nt], 0, 0, 0);
                acc[mt][nt] = __builtin_amdgcn_mfma_f32_16x16x32_bf16(
                    al[mt], bh, acc[mt][nt], 0, 0, 0);
            }
        }
        __syncthreads();
    }

    const int z = n0 >> 10;                   // 0=Q, 1=K, 2=V
    const float* bias = (z == 0) ? bq : ((z == 1) ? bk : bv);
    const float w0 = (float)(2.0 * M_PI / 1024.0);

#pragma unroll
    for (int mt = 0; mt < 4; mt++) {
#pragma unroll
        for (int nt = 0; nt < 4; nt++) {
            int n = n0 + wc * 64 + nt * 16 + l15;
            int f = n & 1023;
            float bsv = bias[f];
            float wl  = (float)(f + 1) * w0;
            float inv = 1.0f / (wl + 1e-8f);
            float phv = phase[f];
#pragma unroll
            for (int r = 0; r < 4; r++) {
                int m  = m0 + wr * 64 + mt * 16 + q * 4 + r;   // row in [0,8192)
                int bb = m >> 12;
                int s  = m & 4095;
                float val = acc[mt][nt][r] + bsv;
                if (z == 2) {
                    Vt[((size_t)bb * 1024 + f) * 4096 + s] = f2b(val);
                } else {
                    float th = fmaf(val, inv, phv);
                    float sn, cs;
                    fast_sincos(th, &sn, &cs);
                    unsigned short* dst = (z == 0) ? Qf : Kf;
                    size_t base = ((size_t)bb * 4096 + s) * 2048;
                    dst[base + f]        = f2b(cs);
                    dst[base + 1024 + f] = f2b(sn);
                }
            }
        }
    }
}

// ---------------- K2/K4: bf16 MFMA NT GEMM ----------------
// C[m][n] = sum_k A[m][k] * Bm[n][k]; 128x128 tile, BK=32, 4 waves (2x2),
// each wave 64x64 via 4x4 mfma_f32_16x16x32_bf16. lda/ldb in elements.
template <typename OutT>
__global__ __launch_bounds__(256) void gemm_nt(
    const unsigned short* __restrict__ A,
    const unsigned short* __restrict__ Bm,
    OutT* __restrict__ C,
    int M, int N, int K, int lda, int ldb)
{
    const int m0 = blockIdx.y * 128;
    const int n0 = blockIdx.x * 128;

    __shared__ unsigned short As[128 * 40];  // stride 40 shorts (pad 8), rows 16B-aligned
    __shared__ unsigned short Bs[128 * 40];

    const int tid  = threadIdx.x;
    const int lane = tid & 63;
    const int w    = tid >> 6;
    const int wr   = w >> 1, wc = w & 1;
    const int l15  = lane & 15, q = lane >> 4;

    f32x4 acc[4][4];
#pragma unroll
    for (int a = 0; a < 4; a++)
#pragma unroll
        for (int b = 0; b < 4; b++) acc[a][b] = (f32x4){0.f, 0.f, 0.f, 0.f};

    for (int k0 = 0; k0 < K; k0 += 32) {
#pragma unroll
        for (int i = 0; i < 2; i++) {
            int idx = tid + 256 * i;          // 0..511 chunks of 8 bf16
            int row = idx >> 2;               // 0..127
            int cc  = idx & 3;                // 0..3 (8 shorts each)
            *(uint4*)&As[row * 40 + cc * 8] =
                *(const uint4*)&A[(size_t)(m0 + row) * lda + k0 + cc * 8];
            *(uint4*)&Bs[row * 40 + cc * 8] =
                *(const uint4*)&Bm[(size_t)(n0 + row) * ldb + k0 + cc * 8];
        }
        __syncthreads();
        bf16x8 af[4], bfr[4];
#pragma unroll
        for (int mt = 0; mt < 4; mt++)
            af[mt] = *(const bf16x8*)&As[(wr * 64 + mt * 16 + l15) * 40 + q * 8];
#pragma unroll
        for (int nt = 0; nt < 4; nt++)
            bfr[nt] = *(const bf16x8*)&Bs[(wc * 64 + nt * 16 + l15) * 40 + q * 8];
#pragma unroll
        for (int mt = 0; mt < 4; mt++)
#pragma unroll
            for (int nt = 0; nt < 4; nt++)
                acc[mt][nt] = __builtin_amdgcn_mfma_f32_16x16x32_bf16(
                    af[mt], bfr[nt], acc[mt][nt], 0, 0, 0);
        __syncthreads();
    }

#pragma unroll
    for (int mt = 0; mt < 4; mt++) {
#pragma unroll
        for (int nt = 0; nt < 4; nt++) {
            int n = n0 + wc * 64 + nt * 16 + l15;
#pragma unroll
            for (int r = 0; r < 4; r++) {
                int m = m0 + wr * 64 + mt * 16 + q * 4 + r;  // C/D: col=lane&15, row=quad*4+reg
                storeC(&C[(size_t)m * N + n], acc[mt][nt][r]);
            }
        }
    }
}

// ---------------- K3: row softmax, fp32 sim -> bf16 P in place ----------------
// One block per row. Reads 4096 fp32 at sim + row*4096; writes 4096 bf16 at
// (ushort*)sim + row*8192 (same byte range start; all reads precede writes).
__global__ __launch_bounds__(256) void softmax_kernel(float* __restrict__ sim)
{
    const size_t row = blockIdx.x;
    const float* pin = sim + row * 4096;
    unsigned short* pout = (unsigned short*)sim + row * 8192;
    const int tid = threadIdx.x;

    float v[16];
#pragma unroll
    for (int i = 0; i < 4; i++) {
        float4 d = ((const float4*)pin)[tid * 4 + i];
        v[4 * i + 0] = d.x * 0.03125f;
        v[4 * i + 1] = d.y * 0.03125f;
        v[4 * i + 2] = d.z * 0.03125f;
        v[4 * i + 3] = d.w * 0.03125f;
    }

    float m = v[0];
#pragma unroll
    for (int i = 1; i < 16; i++) m = fmaxf(m, v[i]);
    for (int o = 32; o > 0; o >>= 1) m = fmaxf(m, __shfl_xor(m, o));
    __shared__ float red[4];
    if ((tid & 63) == 0) red[tid >> 6] = m;
    __syncthreads();
    m = fmaxf(fmaxf(red[0], red[1]), fmaxf(red[2], red[3]));
    __syncthreads();   // protect red[] before reuse

    float e[16];
    float s = 0.f;
#pragma unroll
    for (int i = 0; i < 16; i++) { e[i] = expf(v[i] - m); s += e[i]; }
    for (int o = 32; o > 0; o >>= 1) s += __shfl_xor(s, o);
    if ((tid & 63) == 0) red[tid >> 6] = s;
    __syncthreads();
    float l = (red[0] + red[1]) + (red[2] + red[3]);
    float inv = 1.0f / l;

#pragma unroll
    for (int c = 0; c < 2; c++) {
        unsigned int wds[4];
#pragma unroll
        for (int i = 0; i < 4; i++) {
            unsigned int lo = f2b(e[c * 8 + 2 * i] * inv);
            unsigned int hi = f2b(e[c * 8 + 2 * i + 1] * inv);
            wds[i] = lo | (hi << 16);
        }
        uint4 o4; o4.x = wds[0]; o4.y = wds[1]; o4.z = wds[2]; o4.w = wds[3];
        ((uint4*)pout)[tid * 2 + c] = o4;
    }
}

extern "C" void kernel_launch(void* const* d_in, const int* in_sizes, int n_in,
                              void* d_out, int out_size, void* d_ws, size_t ws_size,
                              hipStream_t stream)
{
    const float* x  = (const float*)d_in[0];
    const float* Wq = (const float*)d_in[1];
    const float* bq = (const float*)d_in[2];
    const float* Wk = (const float*)d_in[3];
    const float* bk = (const float*)d_in[4];
    const float* Wv = (const float*)d_in[5];
    const float* bv = (const float*)d_in[6];
    const float* ph = (const float*)d_in[7];

    char* ws = (char*)d_ws;
    // Region A (first 67.1MB): Xhi|Xlo|Whi|Wlo (46.1MB) before K2; sim fp32 after.
    unsigned short* Xhi = (unsigned short*)ws;                    // 8192*1024
    unsigned short* Xlo = Xhi + (size_t)8192 * 1024;
    unsigned short* Whi = Xlo + (size_t)8192 * 1024;              // 3072*1024 stacked
    unsigned short* Wlo = Whi + (size_t)3072 * 1024;
    float*          sim = (float*)ws;                             // 4096*4096 fp32
    // Region B:
    unsigned short* Qf = (unsigned short*)(ws + (size_t)4096 * 4096 * 4);  // [2][4096][2048]
    unsigned short* Kf = Qf + (size_t)2 * 4096 * 2048;                     // [2][4096][2048]
    unsigned short* Vt = Kf + (size_t)2 * 4096 * 2048;                     // [2][1024][4096]

    // K0: splits
    split_kernel<<<8192, 256, 0, stream>>>(x,  Xhi, Xlo, 8192 * 1024 / 4);
    split_kernel<<<1024, 256, 0, stream>>>(Wq, Whi,                        Wlo,                        1024 * 1024 / 4);
    split_kernel<<<1024, 256, 0, stream>>>(Wk, Whi + (size_t)1024 * 1024,  Wlo + (size_t)1024 * 1024,  1024 * 1024 / 4);
    split_kernel<<<1024, 256, 0, stream>>>(Wv, Whi + (size_t)2048 * 1024,  Wlo + (size_t)2048 * 1024,  1024 * 1024 / 4);

    // K1: split-bf16 MFMA projection + feature epilogue
    proj_kernel<<<dim3(24, 64), 256, 0, stream>>>(Xhi, Xlo, Whi, Wlo,
                                                  bq, bk, bv, ph, Qf, Kf, Vt);

    for (int b = 0; b < 2; b++) {
        const unsigned short* Qb = Qf + (size_t)b * 4096 * 2048;
        const unsigned short* Kb = Kf + (size_t)b * 4096 * 2048;
        const unsigned short* Vb = Vt + (size_t)b * 1024 * 4096;
        float* outb = (float*)d_out + (size_t)b * 4096 * 1024;

        // sim = Qf @ Kf^T, fp32 out
        gemm_nt<float><<<dim3(32, 32), 256, 0, stream>>>(Qb, Kb, sim,
                                                         4096, 4096, 2048, 2048, 2048);
        // softmax rows, bf16 P in place (row stride 8192 shorts)
        softmax_kernel<<<4096, 256, 0, stream>>>(sim);
        // out = P @ Vt^T
        gemm_nt<float><<<dim3(8, 32), 256, 0, stream>>>((const unsigned short*)sim, Vb, outb,
                                                        4096, 1024, 4096, 8192, 4096);
    }
}

// Round 5
// 713.281 us; speedup vs baseline: 1.7150x; 1.0306x over previous
//
#include <hip/hip_runtime.h>
#include <math.h>

// EulerAttention: B=2, S=4096, D=1024.
// Pipeline: [K0] split fp32 -> (hi,lo) bf16 for x and stacked W  (elementwise)
//           [K1] split-bf16 MFMA GEMM (3-term: hh + hl + lh), M=8192 N=3072 K=1024,
//                epilogue: bias + HW-trig sincos -> Qf/Kf bf16 features, V -> Vt bf16
//           per batch b:
//           [K2] bf16 MFMA NT GEMM: sim(fp32) = Qf @ Kf^T  (K=2048)
//           [K3] row softmax: fp32 sim -> bf16 P in place (row stride 8192)
//           [K4] bf16 MFMA NT GEMM: out = P @ Vt^T   (fp32 out)
// ws: [sim 67MB fp32 (aliases Xhi|Xlo|Whi|Wlo 46MB used only before K2)]
//     [Qf 33.5MB][Kf 33.5MB][Vt 16.8MB]  = ~151MB
//
// Precision notes (load-bearing):
//  - sim ~ 640 +- ~15 (cos(small)~1 common mode). sim MUST be fp32 (R1 failure).
//  - Q/K need near-fp32 precision: inv_wl[0]~163 amplifies Q error into theta.
//    3-term split-bf16 leaves ~4e-6 Q error; bf16 feature storage dominates.
//  - R3 failure mode: libm sincosf call + high reg pressure -> scratch spill
//    -> 3.2GB phantom HBM writes. Epilogue trig MUST be branch-free inline
//    (v_sin_f32/v_cos_f32, revolutions input, fract-reduced).
// Perf notes:
//  - R4: proj at 827 TF (plateau); gemm_nt at ~415 TF -> R5 adds
//    global_load_lds width=16 staging (requires UNPADDED stride-32 LDS rows;
//    DMA lands at wave-uniform base + lane*16).

typedef __attribute__((ext_vector_type(8))) short bf16x8;
typedef __attribute__((ext_vector_type(4))) float f32x4;

__device__ __forceinline__ float b2f(unsigned short h) {
    union { unsigned int u; float f; } v; v.u = ((unsigned int)h) << 16; return v.f;
}
__device__ __forceinline__ unsigned short f2b(float f) {
    union { float f; unsigned int u; } v; v.f = f;
    unsigned int r = v.u + 0x7fffu + ((v.u >> 16) & 1u);
    return (unsigned short)(r >> 16);
}
__device__ __forceinline__ void storeC(unsigned short* p, float v) { *p = f2b(v); }
__device__ __forceinline__ void storeC(float* p, float v) { *p = v; }

// Async global->LDS 16B per lane. LDS dest = wave-uniform base + lane*16.
__device__ __forceinline__ void async_load16(const unsigned short* g, unsigned short* l) {
    __builtin_amdgcn_global_load_lds(
        (const __attribute__((address_space(1))) unsigned int*)g,
        (__attribute__((address_space(3))) unsigned int*)l, 16, 0, 0);
}

// Branch-free sin/cos of th (radians). HW v_sin/v_cos take REVOLUTIONS:
// D = sin(S0 * 2pi); reduce to [0,1) via floor.
__device__ __forceinline__ void fast_sincos(float th, float* sn, float* cs) {
    float rev = th * 0.15915494309189535f;   // th / (2*pi)
    float fr  = rev - floorf(rev);           // [0,1)
    float s, c;
    asm("v_sin_f32 %0, %1" : "=v"(s) : "v"(fr));
    asm("v_cos_f32 %0, %1" : "=v"(c) : "v"(fr));
    *sn = s; *cs = c;
}

// ---------------- K0: fp32 -> (hi, lo) bf16 split ----------------
__global__ __launch_bounds__(256) void split_kernel(
    const float* __restrict__ src,
    unsigned short* __restrict__ hi, unsigned short* __restrict__ lo, int n4)
{
    int i = blockIdx.x * 256 + threadIdx.x;
    if (i >= n4) return;
    float4 v = ((const float4*)src)[i];
    float f[4] = { v.x, v.y, v.z, v.w };
    unsigned short h[4], l[4];
#pragma unroll
    for (int j = 0; j < 4; j++) {
        h[j] = f2b(f[j]);
        float r = f[j] - b2f(h[j]);
        l[j] = f2b(r);
    }
    uint2 ho, lv;
    ho.x = (unsigned int)h[0] | ((unsigned int)h[1] << 16);
    ho.y = (unsigned int)h[2] | ((unsigned int)h[3] << 16);
    lv.x = (unsigned int)l[0] | ((unsigned int)l[1] << 16);
    lv.y = (unsigned int)l[2] | ((unsigned int)l[3] << 16);
    ((uint2*)hi)[i] = ho;
    ((uint2*)lo)[i] = lv;
}

// W splits fused: grid.y picks Wq/Wk/Wv -> stacked hi/lo at y*1024*1024.
__global__ __launch_bounds__(256) void split_w_kernel(
    const float* __restrict__ Wq, const float* __restrict__ Wk,
    const float* __restrict__ Wv,
    unsigned short* __restrict__ hi, unsigned short* __restrict__ lo)
{
    const int y = blockIdx.y;
    const float* src = (y == 0) ? Wq : ((y == 1) ? Wk : Wv);
    size_t off4 = (size_t)y * (1024 * 1024 / 4);
    int i = blockIdx.x * 256 + threadIdx.x;   // < 1024*1024/4
    float4 v = ((const float4*)src)[i];
    float f[4] = { v.x, v.y, v.z, v.w };
    unsigned short h[4], l[4];
#pragma unroll
    for (int j = 0; j < 4; j++) {
        h[j] = f2b(f[j]);
        float r = f[j] - b2f(h[j]);
        l[j] = f2b(r);
    }
    uint2 ho, lv;
    ho.x = (unsigned int)h[0] | ((unsigned int)h[1] << 16);
    ho.y = (unsigned int)h[2] | ((unsigned int)h[3] << 16);
    lv.x = (unsigned int)l[0] | ((unsigned int)l[1] << 16);
    lv.y = (unsigned int)l[2] | ((unsigned int)l[3] << 16);
    ((uint2*)hi)[off4 + i] = ho;
    ((uint2*)lo)[off4 + i] = lv;
}

// ---------------- K1: split-bf16 MFMA projection GEMM ----------------
// C = X@W^T via 3-term split; grid (24, 64): n0 = bx*128 in [0,3072), m0 = by*128.
// n-blocks 0-7 -> Q, 8-15 -> K, 16-23 -> V (z = n0>>10, uniform per block).
__global__ __launch_bounds__(256, 2) void proj_kernel(
    const unsigned short* __restrict__ Xhi, const unsigned short* __restrict__ Xlo,
    const unsigned short* __restrict__ Whi, const unsigned short* __restrict__ Wlo,
    const float* __restrict__ bq, const float* __restrict__ bk,
    const float* __restrict__ bv, const float* __restrict__ phase,
    unsigned short* __restrict__ Qf, unsigned short* __restrict__ Kf,
    unsigned short* __restrict__ Vt)
{
    const int m0 = blockIdx.y * 128;
    const int n0 = blockIdx.x * 128;

    __shared__ unsigned short Ah[128 * 40], Al[128 * 40];
    __shared__ unsigned short Bh[128 * 40], Bl[128 * 40];

    const int tid  = threadIdx.x;
    const int lane = tid & 63;
    const int w    = tid >> 6;
    const int wr   = w >> 1, wc = w & 1;
    const int l15  = lane & 15, q = lane >> 4;

    f32x4 acc[4][4];
#pragma unroll
    for (int a = 0; a < 4; a++)
#pragma unroll
        for (int b = 0; b < 4; b++) acc[a][b] = (f32x4){0.f, 0.f, 0.f, 0.f};

    for (int k0 = 0; k0 < 1024; k0 += 32) {
#pragma unroll
        for (int i = 0; i < 2; i++) {
            int idx = tid + 256 * i;
            int row = idx >> 2;
            int cc  = idx & 3;
            size_t ga = (size_t)(m0 + row) * 1024 + k0 + cc * 8;
            size_t gb = (size_t)(n0 + row) * 1024 + k0 + cc * 8;
            *(uint4*)&Ah[row * 40 + cc * 8] = *(const uint4*)&Xhi[ga];
            *(uint4*)&Al[row * 40 + cc * 8] = *(const uint4*)&Xlo[ga];
            *(uint4*)&Bh[row * 40 + cc * 8] = *(const uint4*)&Whi[gb];
            *(uint4*)&Bl[row * 40 + cc * 8] = *(const uint4*)&Wlo[gb];
        }
        __syncthreads();
        bf16x8 ah[4], al[4];
#pragma unroll
        for (int mt = 0; mt < 4; mt++) {
            int off = (wr * 64 + mt * 16 + l15) * 40 + q * 8;
            ah[mt] = *(const bf16x8*)&Ah[off];
            al[mt] = *(const bf16x8*)&Al[off];
        }
#pragma unroll
        for (int nt = 0; nt < 4; nt++) {
            int off = (wc * 64 + nt * 16 + l15) * 40 + q * 8;
            bf16x8 bh = *(const bf16x8*)&Bh[off];
            bf16x8 bl = *(const bf16x8*)&Bl[off];
#pragma unroll
            for (int mt = 0; mt < 4; mt++) {
                acc[mt][nt] = __builtin_amdgcn_mfma_f32_16x16x32_bf16(
                    ah[mt], bh, acc[mt][nt], 0, 0, 0);
                acc[mt][nt] = __builtin_amdgcn_mfma_f32_16x16x32_bf16(
                    ah[mt], bl, acc[mt][nt], 0, 0, 0);
                acc[mt][nt] = __builtin_amdgcn_mfma_f32_16x16x32_bf16(
                    al[mt], bh, acc[mt][nt], 0, 0, 0);
            }
        }
        __syncthreads();
    }

    const int z = n0 >> 10;                   // 0=Q, 1=K, 2=V
    const float* bias = (z == 0) ? bq : ((z == 1) ? bk : bv);
    const float w0 = (float)(2.0 * M_PI / 1024.0);

#pragma unroll
    for (int mt = 0; mt < 4; mt++) {
#pragma unroll
        for (int nt = 0; nt < 4; nt++) {
            int n = n0 + wc * 64 + nt * 16 + l15;
            int f = n & 1023;
            float bsv = bias[f];
            float wl  = (float)(f + 1) * w0;
            float inv = 1.0f / (wl + 1e-8f);
            float phv = phase[f];
#pragma unroll
            for (int r = 0; r < 4; r++) {
                int m  = m0 + wr * 64 + mt * 16 + q * 4 + r;   // row in [0,8192)
                int bb = m >> 12;
                int s  = m & 4095;
                float val = acc[mt][nt][r] + bsv;
                if (z == 2) {
                    Vt[((size_t)bb * 1024 + f) * 4096 + s] = f2b(val);
                } else {
                    float th = fmaf(val, inv, phv);
                    float sn, cs;
                    fast_sincos(th, &sn, &cs);
                    unsigned short* dst = (z == 0) ? Qf : Kf;
                    size_t base = ((size_t)bb * 4096 + s) * 2048;
                    dst[base + f]        = f2b(cs);
                    dst[base + 1024 + f] = f2b(sn);
                }
            }
        }
    }
}

// ---------------- K2/K4: bf16 MFMA NT GEMM (global_load_lds staging) -------
// C[m][n] = sum_k A[m][k] * Bm[n][k]; 128x128 tile, BK=32, 4 waves (2x2),
// each wave 64x64 via 4x4 mfma_f32_16x16x32_bf16. lda/ldb in elements.
// LDS rows UNPADDED stride 32 shorts: global_load_lds lands lane i's 16B at
// base + i*16; mapping row=lane>>2, col=(lane&3)*8 makes that exactly
// row-major-32. Wave w issues chunks (2w, 2w+1), each = 16 rows.
template <typename OutT>
__global__ __launch_bounds__(256) void gemm_nt(
    const unsigned short* __restrict__ A,
    const unsigned short* __restrict__ Bm,
    OutT* __restrict__ C,
    int M, int N, int K, int lda, int ldb)
{
    const int m0 = blockIdx.y * 128;
    const int n0 = blockIdx.x * 128;

    __shared__ unsigned short As[128 * 32];
    __shared__ unsigned short Bs[128 * 32];

    const int tid  = threadIdx.x;
    const int lane = tid & 63;
    const int w    = tid >> 6;
    const int wr   = w >> 1, wc = w & 1;
    const int l15  = lane & 15, q = lane >> 4;
    const int lrow = lane >> 2;          // 0..15
    const int lcol = (lane & 3) * 8;     // shorts

    f32x4 acc[4][4];
#pragma unroll
    for (int a = 0; a < 4; a++)
#pragma unroll
        for (int b = 0; b < 4; b++) acc[a][b] = (f32x4){0.f, 0.f, 0.f, 0.f};

    for (int k0 = 0; k0 < K; k0 += 32) {
#pragma unroll
        for (int i = 0; i < 2; i++) {
            int chunk = w * 2 + i;       // 0..7 -> rows [chunk*16, chunk*16+16)
            async_load16(&A[(size_t)(m0 + chunk * 16 + lrow) * lda + k0 + lcol],
                         &As[chunk * 512]);
            async_load16(&Bm[(size_t)(n0 + chunk * 16 + lrow) * ldb + k0 + lcol],
                         &Bs[chunk * 512]);
        }
        __syncthreads();
        bf16x8 af[4], bfr[4];
#pragma unroll
        for (int mt = 0; mt < 4; mt++)
            af[mt] = *(const bf16x8*)&As[(wr * 64 + mt * 16 + l15) * 32 + q * 8];
#pragma unroll
        for (int nt = 0; nt < 4; nt++)
            bfr[nt] = *(const bf16x8*)&Bs[(wc * 64 + nt * 16 + l15) * 32 + q * 8];
#pragma unroll
        for (int mt = 0; mt < 4; mt++)
#pragma unroll
            for (int nt = 0; nt < 4; nt++)
                acc[mt][nt] = __builtin_amdgcn_mfma_f32_16x16x32_bf16(
                    af[mt], bfr[nt], acc[mt][nt], 0, 0, 0);
        __syncthreads();
    }

#pragma unroll
    for (int mt = 0; mt < 4; mt++) {
#pragma unroll
        for (int nt = 0; nt < 4; nt++) {
            int n = n0 + wc * 64 + nt * 16 + l15;
#pragma unroll
            for (int r = 0; r < 4; r++) {
                int m = m0 + wr * 64 + mt * 16 + q * 4 + r;  // C/D: col=lane&15, row=quad*4+reg
                storeC(&C[(size_t)m * N + n], acc[mt][nt][r]);
            }
        }
    }
}

// ---------------- K3: row softmax, fp32 sim -> bf16 P in place ----------------
// One block per row. Reads 4096 fp32 at sim + row*4096; writes 4096 bf16 at
// (ushort*)sim + row*8192 (same byte range start; all reads precede writes).
__global__ __launch_bounds__(256) void softmax_kernel(float* __restrict__ sim)
{
    const size_t row = blockIdx.x;
    const float* pin = sim + row * 4096;
    unsigned short* pout = (unsigned short*)sim + row * 8192;
    const int tid = threadIdx.x;

    float v[16];
#pragma unroll
    for (int i = 0; i < 4; i++) {
        float4 d = ((const float4*)pin)[tid * 4 + i];
        v[4 * i + 0] = d.x * 0.03125f;
        v[4 * i + 1] = d.y * 0.03125f;
        v[4 * i + 2] = d.z * 0.03125f;
        v[4 * i + 3] = d.w * 0.03125f;
    }

    float m = v[0];
#pragma unroll
    for (int i = 1; i < 16; i++) m = fmaxf(m, v[i]);
    for (int o = 32; o > 0; o >>= 1) m = fmaxf(m, __shfl_xor(m, o));
    __shared__ float red[4];
    if ((tid & 63) == 0) red[tid >> 6] = m;
    __syncthreads();
    m = fmaxf(fmaxf(red[0], red[1]), fmaxf(red[2], red[3]));
    __syncthreads();   // protect red[] before reuse

    float e[16];
    float s = 0.f;
#pragma unroll
    for (int i = 0; i < 16; i++) { e[i] = expf(v[i] - m); s += e[i]; }
    for (int o = 32; o > 0; o >>= 1) s += __shfl_xor(s, o);
    if ((tid & 63) == 0) red[tid >> 6] = s;
    __syncthreads();
    float l = (red[0] + red[1]) + (red[2] + red[3]);
    float inv = 1.0f / l;

#pragma unroll
    for (int c = 0; c < 2; c++) {
        unsigned int wds[4];
#pragma unroll
        for (int i = 0; i < 4; i++) {
            unsigned int lo = f2b(e[c * 8 + 2 * i] * inv);
            unsigned int hi = f2b(e[c * 8 + 2 * i + 1] * inv);
            wds[i] = lo | (hi << 16);
        }
        uint4 o4; o4.x = wds[0]; o4.y = wds[1]; o4.z = wds[2]; o4.w = wds[3];
        ((uint4*)pout)[tid * 2 + c] = o4;
    }
}

extern "C" void kernel_launch(void* const* d_in, const int* in_sizes, int n_in,
                              void* d_out, int out_size, void* d_ws, size_t ws_size,
                              hipStream_t stream)
{
    const float* x  = (const float*)d_in[0];
    const float* Wq = (const float*)d_in[1];
    const float* bq = (const float*)d_in[2];
    const float* Wk = (const float*)d_in[3];
    const float* bk = (const float*)d_in[4];
    const float* Wv = (const float*)d_in[5];
    const float* bv = (const float*)d_in[6];
    const float* ph = (const float*)d_in[7];

    char* ws = (char*)d_ws;
    // Region A (first 67.1MB): Xhi|Xlo|Whi|Wlo (46.1MB) before K2; sim fp32 after.
    unsigned short* Xhi = (unsigned short*)ws;                    // 8192*1024
    unsigned short* Xlo = Xhi + (size_t)8192 * 1024;
    unsigned short* Whi = Xlo + (size_t)8192 * 1024;              // 3072*1024 stacked
    unsigned short* Wlo = Whi + (size_t)3072 * 1024;
    float*          sim = (float*)ws;                             // 4096*4096 fp32
    // Region B:
    unsigned short* Qf = (unsigned short*)(ws + (size_t)4096 * 4096 * 4);  // [2][4096][2048]
    unsigned short* Kf = Qf + (size_t)2 * 4096 * 2048;                     // [2][4096][2048]
    unsigned short* Vt = Kf + (size_t)2 * 4096 * 2048;                     // [2][1024][4096]

    // K0: splits
    split_kernel<<<8192, 256, 0, stream>>>(x, Xhi, Xlo, 8192 * 1024 / 4);
    split_w_kernel<<<dim3(1024, 3), 256, 0, stream>>>(Wq, Wk, Wv, Whi, Wlo);

    // K1: split-bf16 MFMA projection + feature epilogue
    proj_kernel<<<dim3(24, 64), 256, 0, stream>>>(Xhi, Xlo, Whi, Wlo,
                                                  bq, bk, bv, ph, Qf, Kf, Vt);

    for (int b = 0; b < 2; b++) {
        const unsigned short* Qb = Qf + (size_t)b * 4096 * 2048;
        const unsigned short* Kb = Kf + (size_t)b * 4096 * 2048;
        const unsigned short* Vb = Vt + (size_t)b * 1024 * 4096;
        float* outb = (float*)d_out + (size_t)b * 4096 * 1024;

        // sim = Qf @ Kf^T, fp32 out
        gemm_nt<float><<<dim3(32, 32), 256, 0, stream>>>(Qb, Kb, sim,
                                                         4096, 4096, 2048, 2048, 2048);
        // softmax rows, bf16 P in place (row stride 8192 shorts)
        softmax_kernel<<<4096, 256, 0, stream>>>(sim);
        // out = P @ Vt^T
        gemm_nt<float><<<dim3(8, 32), 256, 0, stream>>>((const unsigned short*)sim, Vb, outb,
                                                        4096, 1024, 4096, 8192, 4096);
    }
}